// Round 6
// baseline (387.272 us; speedup 1.0000x reference)
//
#include <hip/hip_runtime.h>
#include <hip/hip_bf16.h>

using bf16 = __hip_bfloat16;
typedef __attribute__((ext_vector_type(8))) short s16x8;   // 8 bf16 = 4 VGPRs
typedef __attribute__((ext_vector_type(4))) float f32x4;

// ---- async global->LDS 16B copy (wave-uniform LDS base + lane*16) ----
__device__ __forceinline__ void async_cp16(const void* g, void* lds) {
    __builtin_amdgcn_global_load_lds(
        (const __attribute__((address_space(1))) unsigned int*)g,
        (__attribute__((address_space(3))) unsigned int*)lds,
        16, 0, 0);
}

__device__ __forceinline__ void storeC(float* p, float v) { *p = v; }
__device__ __forceinline__ void storeC(bf16* p, float v) { *p = __float2bfloat16(v); }

// ---------------------------------------------------------------------------
// weights f32 -> bf16 (blockIdx.y = 0..3 selects tensor), y==4 zeroes colsum
// ---------------------------------------------------------------------------
__global__ __launch_bounds__(256) void cvt4z_kernel(
    const float* __restrict__ s0, const float* __restrict__ s1,
    const float* __restrict__ s2, const float* __restrict__ s3,
    bf16* __restrict__ dst, int n4, float* __restrict__ csm, int ncsm4)
{
    const int i = blockIdx.x * 256 + threadIdx.x;
    if (blockIdx.y == 4) {
        if (i < ncsm4) ((float4*)csm)[i] = float4{0.f, 0.f, 0.f, 0.f};
        return;
    }
    if (i >= n4) return;
    const float* src = (blockIdx.y == 0) ? s0 : (blockIdx.y == 1) ? s1
                     : (blockIdx.y == 2) ? s2 : s3;
    float4 v = ((const float4*)src)[i];
    union { bf16 h[4]; uint2 u; } o;
    o.h[0] = __float2bfloat16(v.x);
    o.h[1] = __float2bfloat16(v.y);
    o.h[2] = __float2bfloat16(v.z);
    o.h[3] = __float2bfloat16(v.w);
    ((uint2*)(dst + (size_t)blockIdx.y * (size_t)n4 * 4))[i] = o.u;
}

// ---------------------------------------------------------------------------
// In-place: Vp[h,i] /= colsum[z*NK + i]   (8 elems/thread along i)
// ---------------------------------------------------------------------------
__global__ __launch_bounds__(256) void scale_cols_kernel(
    bf16* __restrict__ Vp, const float* __restrict__ colsum, int HN, int NKc)
{
    const long long idx = ((long long)blockIdx.x * 256 + threadIdx.x) * 8;
    const int z = (int)(idx / HN);
    const int i = (int)(idx % NKc);
    union { uint4 u; bf16 h[8]; } in, o;
    in.u = *(const uint4*)(Vp + idx);
    const float4 c0 = *(const float4*)(colsum + (long long)z * NKc + i);
    const float4 c1 = *(const float4*)(colsum + (long long)z * NKc + i + 4);
    o.h[0] = __float2bfloat16(__bfloat162float(in.h[0]) / c0.x);
    o.h[1] = __float2bfloat16(__bfloat162float(in.h[1]) / c0.y);
    o.h[2] = __float2bfloat16(__bfloat162float(in.h[2]) / c0.z);
    o.h[3] = __float2bfloat16(__bfloat162float(in.h[3]) / c0.w);
    o.h[4] = __float2bfloat16(__bfloat162float(in.h[4]) / c1.x);
    o.h[5] = __float2bfloat16(__bfloat162float(in.h[5]) / c1.y);
    o.h[6] = __float2bfloat16(__bfloat162float(in.h[6]) / c1.z);
    o.h[7] = __float2bfloat16(__bfloat162float(in.h[7]) / c1.w);
    *(uint4*)(Vp + idx) = o.u;
}

// ---------------------------------------------------------------------------
// NT GEMM: C[M,N] = scale * (A[M,K] @ B[N,K]^T) + bias
//   Tile 128xBN, BK=64, 256 threads (4 waves), XOR-swizzled LDS (conflict-free)
//   BIAS: 0 none, 1 bias[col], 2 bias[row]
//   SWZ: 1 = 1-D grid, z = bid % nz (XCD binding), GROUP_M=4 tile order
//   EXP: 1 = write exp(acc*scale), atomic per-column sums into colsum[bz*N+col]
//   CVT: bit0 = A operand is f32 (convert during staging), bit1 = B is f32
// ---------------------------------------------------------------------------
template <typename OutT, int BIAS, int BN, int SWZ = 0, int EXP = 0, int CVT = 0>
__global__ __launch_bounds__(256) void gemm_nt(
    const void* __restrict__ Av, const void* __restrict__ Bv,
    OutT* __restrict__ C, const float* __restrict__ bias,
    float* __restrict__ colsum,
    int M, int N, int K,
    long long sA, long long sB, long long sC,
    float scale, int nz, int npn)
{
    constexpr int NF = BN / 32;              // B frags per wave (n-dir)
    __shared__ __align__(16) bf16 As[128 * 64];
    __shared__ __align__(16) bf16 Bs[BN * 64];

    int bz, m0, n0;
    if constexpr (SWZ) {
        const int bid = blockIdx.x;
        bz = bid % nz;                        // bind batch -> XCD (round-robin)
        const int t0 = bid / nz;
        const int grp = t0 / (4 * npn);       // GROUP_M = 4
        m0 = (grp * 4 + (t0 % 4)) * 128;
        n0 = ((t0 / 4) % npn) * BN;
    } else {
        bz = blockIdx.z;
        m0 = blockIdx.y * 128;
        n0 = blockIdx.x * BN;
    }
    C += sC * bz;

    const bf16*  A16 = nullptr; const float* A32 = nullptr;
    const bf16*  B16 = nullptr; const float* B32 = nullptr;
    if constexpr (CVT & 1) A32 = (const float*)Av + sA * bz;
    else                   A16 = (const bf16*)Av + sA * bz;
    if constexpr (CVT & 2) B32 = (const float*)Bv + sB * bz;
    else                   B16 = (const bf16*)Bv + sB * bz;

    const int t = threadIdx.x;
    const int lane = t & 63;
    const int w = t >> 6;                    // wave id 0..3
    const int wm = (w >> 1) * 64;            // wave row offset
    const int wn = (w & 1) * (BN / 2);       // wave col offset

    f32x4 acc[4][NF] = {};

    // staging: idx = c*256+t -> row = idx>>3 ; SWIZZLED source col8 = (t&7)^(row&7)
    const int trow = t >> 3;
    const int tcol = (t & 7) ^ (trow & 7);
    char* AsB = (char*)As + (size_t)w * 1024;    // async: + c*4096 (wave-uniform)
    char* BsB = (char*)Bs + (size_t)w * 1024;

    for (int k0 = 0; k0 < K; k0 += 64) {
        __syncthreads();   // protect LDS while other waves still compute
        if constexpr (CVT & 1) {
            const float* af = A32 + (long long)(m0 + trow) * K + k0 + tcol * 8;
#pragma unroll
            for (int c = 0; c < 4; ++c) {
                float4 v0 = *(const float4*)(af + (long long)(c * 32) * K);
                float4 v1 = *(const float4*)(af + (long long)(c * 32) * K + 4);
                union { bf16 h[8]; uint4 u; } o;
                o.h[0] = __float2bfloat16(v0.x); o.h[1] = __float2bfloat16(v0.y);
                o.h[2] = __float2bfloat16(v0.z); o.h[3] = __float2bfloat16(v0.w);
                o.h[4] = __float2bfloat16(v1.x); o.h[5] = __float2bfloat16(v1.y);
                o.h[6] = __float2bfloat16(v1.z); o.h[7] = __float2bfloat16(v1.w);
                *(uint4*)((char*)As + (size_t)(c * 256 + t) * 16) = o.u;
            }
        } else {
            const bf16* a_src = A16 + (long long)(m0 + trow) * K + k0 + tcol * 8;
#pragma unroll
            for (int c = 0; c < 4; ++c)
                async_cp16(a_src + (long long)(c * 32) * K, AsB + c * 4096);
        }
        if constexpr (CVT & 2) {
            const float* bf = B32 + (long long)(n0 + trow) * K + k0 + tcol * 8;
#pragma unroll
            for (int c = 0; c < NF; ++c) {
                float4 v0 = *(const float4*)(bf + (long long)(c * 32) * K);
                float4 v1 = *(const float4*)(bf + (long long)(c * 32) * K + 4);
                union { bf16 h[8]; uint4 u; } o;
                o.h[0] = __float2bfloat16(v0.x); o.h[1] = __float2bfloat16(v0.y);
                o.h[2] = __float2bfloat16(v0.z); o.h[3] = __float2bfloat16(v0.w);
                o.h[4] = __float2bfloat16(v1.x); o.h[5] = __float2bfloat16(v1.y);
                o.h[6] = __float2bfloat16(v1.z); o.h[7] = __float2bfloat16(v1.w);
                *(uint4*)((char*)Bs + (size_t)(c * 256 + t) * 16) = o.u;
            }
        } else {
            const bf16* b_src = B16 + (long long)(n0 + trow) * K + k0 + tcol * 8;
#pragma unroll
            for (int c = 0; c < NF; ++c)
                async_cp16(b_src + (long long)(c * 32) * K, BsB + c * 4096);
        }
        __syncthreads();   // drains vmcnt + lgkmcnt before s_barrier

        const int rl = lane & 15;
        const int quad = lane >> 4;
        const int sw = rl & 7;
#pragma unroll
        for (int kk = 0; kk < 64; kk += 32) {
            const int c8 = (kk >> 3) + quad;          // logical col8
            const int ko = ((c8 ^ sw) << 3);          // physical element offset
            s16x8 af[4], bfr[NF];
#pragma unroll
            for (int i = 0; i < 4; ++i)
                af[i] = *(const s16x8*)(As + (wm + i * 16 + rl) * 64 + ko);
#pragma unroll
            for (int j = 0; j < NF; ++j)
                bfr[j] = *(const s16x8*)(Bs + (wn + j * 16 + rl) * 64 + ko);
#pragma unroll
            for (int i = 0; i < 4; ++i)
#pragma unroll
                for (int j = 0; j < NF; ++j)
                    acc[i][j] = __builtin_amdgcn_mfma_f32_16x16x32_bf16(
                        af[i], bfr[j], acc[i][j], 0, 0, 0);
        }
    }

    // epilogue: D row = (lane>>4)*4 + r, col = lane&15  (verified m89/m91)
    const int cl = lane & 15;
    const int rquad = (lane >> 4) << 2;
#pragma unroll
    for (int tn = 0; tn < NF; ++tn) {
        const int col = n0 + wn + tn * 16 + cl;
        if constexpr (EXP) {
            float csum = 0.f;
#pragma unroll
            for (int tm = 0; tm < 4; ++tm) {
#pragma unroll
                for (int r = 0; r < 4; ++r) {
                    const int row = m0 + wm + tm * 16 + rquad + r;
                    float v = __expf(acc[tm][tn][r] * scale);
                    csum += v;
                    storeC(C + (long long)row * N + col, v);
                }
            }
            csum += __shfl_xor(csum, 16);
            csum += __shfl_xor(csum, 32);
            if ((lane >> 4) == 0)
                atomicAdd(&colsum[(long long)bz * N + col], csum);
        } else {
            float bcol = 0.f;
            if constexpr (BIAS == 1) bcol = bias[col];
#pragma unroll
            for (int tm = 0; tm < 4; ++tm) {
#pragma unroll
                for (int r = 0; r < 4; ++r) {
                    const int row = m0 + wm + tm * 16 + rquad + r;
                    float v = acc[tm][tn][r] * scale;
                    if constexpr (BIAS == 1) v += bcol;
                    if constexpr (BIAS == 2) v += bias[row];
                    storeC(C + (long long)row * N + col, v);
                }
            }
        }
    }
}

// ---------------------------------------------------------------------------
extern "C" void kernel_launch(void* const* d_in, const int* in_sizes, int n_in,
                              void* d_out, int out_size, void* d_ws, size_t ws_size,
                              hipStream_t stream)
{
    constexpr int Bb = 8, NK = 2048, NQ = 2048, D = 256, H = 1024;
    const float scale = 0.03125f;   // 1/sqrt(1024)
    constexpr size_t E1  = (size_t)Bb * NK * H;   // 16,777,216 elems (33.55 MB bf16)
    constexpr size_t ES  = (size_t)NK * NQ;       // 4,194,304 elems per batch
    constexpr size_t EV  = (size_t)H * NK;        // 2,097,152 elems per batch
    constexpr size_t WSZ = (size_t)H * D;         // 262,144 elems
    constexpr size_t MISC = 4 * WSZ * 2 + (size_t)8 * NK * 4 + 256;

    const float* KEY   = (const float*)d_in[0];
    const float* VALUE = (const float*)d_in[1];
    const float* QUERY = (const float*)d_in[2];
    const float* Wk_w  = (const float*)d_in[3];
    const float* Wk_b  = (const float*)d_in[4];
    const float* Wq_w  = (const float*)d_in[5];
    const float* Wq_b  = (const float*)d_in[6];
    const float* Wv_w  = (const float*)d_in[7];
    const float* Wv_b  = (const float*)d_in[8];
    const float* lin_w = (const float*)d_in[9];
    const float* lin_b = (const float*)d_in[10];
    float* out = (float*)d_out;

    // group size: largest g whose workspace fits (deterministic across calls)
    auto need = [&](int g) -> size_t {
        return 3 * E1 * 2 + (g < 8 ? E1 * 2 : 0) + (size_t)g * ES * 2 + MISC;
    };
    const int g = (ws_size >= need(8)) ? 8 : (ws_size >= need(4)) ? 4 : 2;

    char* ws = (char*)d_ws;
    bf16* Kp   = (bf16*)ws;  ws += E1 * 2;
    bf16* Qp   = (bf16*)ws;  ws += E1 * 2;
    bf16* VpT  = (bf16*)ws;  ws += E1 * 2;                 // [b][h][i]
    bf16* ctx  = Kp;                                       // g==8: alias dead Kp
    if (g < 8) { ctx = (bf16*)ws; ws += E1 * 2; }
    bf16* Sg   = (bf16*)ws;  ws += (size_t)g * ES * 2;     // STexp[k,i], bf16
    float* csm = (float*)ws; ws += (size_t)8 * NK * 4;     // column sums (global batch)
    bf16* Wkb  = (bf16*)ws;  ws += WSZ * 2;
    bf16* Wqb  = (bf16*)ws;  ws += WSZ * 2;
    bf16* Wvb  = (bf16*)ws;  ws += WSZ * 2;
    bf16* linb = (bf16*)ws;  ws += WSZ * 2;

    dim3 blk(256);

    // 0: weights f32 -> bf16 (4 tensors) + zero csm (grid.y == 4)
    {
        const int n4w = (int)(WSZ / 4);
        cvt4z_kernel<<<dim3(n4w / 256, 5), blk, 0, stream>>>(
            Wk_w, Wq_w, Wv_w, lin_w, Wkb, n4w, csm, 8 * NK / 4);
    }

    // 1,2: projections K,Q  (M=16384, N=H, K=D) + col bias; A read as f32
    gemm_nt<bf16, 1, 128, 0, 0, 1><<<dim3(H / 128, Bb * NK / 128, 1), blk, 0, stream>>>(
        KEY, Wkb, Kp, Wk_b, nullptr, Bb * NK, H, D, 0, 0, 0, 1.0f, 1, 1);
    gemm_nt<bf16, 1, 128, 0, 0, 1><<<dim3(H / 128, Bb * NQ / 128, 1), blk, 0, stream>>>(
        QUERY, Wqb, Qp, Wq_b, nullptr, Bb * NQ, H, D, 0, 0, 0, 1.0f, 1, 1);

    // 3: VpT[b,h,i] = Wv_w @ VALUE[b]^T + Wv_b(row); B read as f32 (z=batch)
    gemm_nt<bf16, 2, 128, 0, 0, 2><<<dim3(NK / 128, H / 128, Bb), blk, 0, stream>>>(
        Wvb, VALUE, VpT, Wv_b, nullptr, H, NK, D,
        0, (long long)NK * D, (long long)H * NK, 1.0f, 1, 1);

    // 4..6 per group of g batches
    for (int b0 = 0; b0 < Bb; b0 += g) {
        // 4: STexp[k,i] = exp(scale * Qp[b] @ Kp[b]^T), colsum[b,i] += col sums
        gemm_nt<bf16, 0, 128, 1, 1, 0><<<dim3(g * (NQ / 128) * (NK / 128)), blk, 0, stream>>>(
            Qp + (size_t)b0 * NQ * H, Kp + (size_t)b0 * NK * H, Sg, nullptr,
            csm + (size_t)b0 * NK,
            NQ, NK, H,
            (long long)NQ * H, (long long)NK * H, (long long)NQ * NK, scale,
            g, NK / 128);
        // 5: VpT[h,i] /= colsum[i]  (in place)
        scale_cols_kernel<<<dim3((int)(g * EV / 8 / 256)), blk, 0, stream>>>(
            VpT + (size_t)b0 * EV, csm + (size_t)b0 * NK, (int)EV, NK);
        // 6: ctx[k,h] = STexp @ VpT_scaled^T   (M=NQ, N=H, K=NK, swizzled)
        gemm_nt<bf16, 0, 128, 1, 0, 0><<<dim3(g * (NQ / 128) * (H / 128)), blk, 0, stream>>>(
            Sg, VpT + (size_t)b0 * EV, ctx + (size_t)b0 * NQ * H, nullptr, nullptr,
            NQ, H, NK,
            (long long)NQ * NK, (long long)H * NK, (long long)NQ * H, 1.0f,
            g, H / 128);
    }

    // 7: out = ctx @ lin_w^T + lin_b   (M=16384, N=D, K=H) -> f32 d_out, BN=64
    gemm_nt<float, 1, 64, 0, 0, 0><<<dim3(D / 64, Bb * NQ / 128, 1), blk, 0, stream>>>(
        ctx, linb, out, lin_b, nullptr, Bb * NQ, D, H, 0, 0, 0, 1.0f, 1, 1);
}

// Round 7
// 361.875 us; speedup vs baseline: 1.0702x; 1.0702x over previous
//
#include <hip/hip_runtime.h>
#include <hip/hip_bf16.h>

using bf16 = __hip_bfloat16;
typedef __attribute__((ext_vector_type(8))) short s16x8;   // 8 bf16 = 4 VGPRs
typedef __attribute__((ext_vector_type(4))) float f32x4;

// ---- async global->LDS 16B copy (wave-uniform LDS base + lane*16) ----
__device__ __forceinline__ void async_cp16(const void* g, void* lds) {
    __builtin_amdgcn_global_load_lds(
        (const __attribute__((address_space(1))) unsigned int*)g,
        (__attribute__((address_space(3))) unsigned int*)lds,
        16, 0, 0);
}

__device__ __forceinline__ void storeC(float* p, float v) { *p = v; }
__device__ __forceinline__ void storeC(bf16* p, float v) { *p = __float2bfloat16(v); }

// pack 8 f32 -> s16x8 bf16 fragment
__device__ __forceinline__ s16x8 pack8(float4 a, float4 b) {
    union { bf16 h[8]; s16x8 v; } o;
    o.h[0] = __float2bfloat16(a.x); o.h[1] = __float2bfloat16(a.y);
    o.h[2] = __float2bfloat16(a.z); o.h[3] = __float2bfloat16(a.w);
    o.h[4] = __float2bfloat16(b.x); o.h[5] = __float2bfloat16(b.y);
    o.h[6] = __float2bfloat16(b.z); o.h[7] = __float2bfloat16(b.w);
    return o.v;
}

// ---------------------------------------------------------------------------
// weights f32 -> bf16 (blockIdx.y = 0..3 selects tensor), y==4 zeroes colsum
// ---------------------------------------------------------------------------
__global__ __launch_bounds__(256) void cvt4z_kernel(
    const float* __restrict__ s0, const float* __restrict__ s1,
    const float* __restrict__ s2, const float* __restrict__ s3,
    bf16* __restrict__ dst, int n4, float* __restrict__ csm, int ncsm4)
{
    const int i = blockIdx.x * 256 + threadIdx.x;
    if (blockIdx.y == 4) {
        if (i < ncsm4) ((float4*)csm)[i] = float4{0.f, 0.f, 0.f, 0.f};
        return;
    }
    if (i >= n4) return;
    const float* src = (blockIdx.y == 0) ? s0 : (blockIdx.y == 1) ? s1
                     : (blockIdx.y == 2) ? s2 : s3;
    float4 v = ((const float4*)src)[i];
    union { bf16 h[4]; uint2 u; } o;
    o.h[0] = __float2bfloat16(v.x);
    o.h[1] = __float2bfloat16(v.y);
    o.h[2] = __float2bfloat16(v.z);
    o.h[3] = __float2bfloat16(v.w);
    ((uint2*)(dst + (size_t)blockIdx.y * (size_t)n4 * 4))[i] = o.u;
}

// ---------------------------------------------------------------------------
// NT GEMM: C[M,N] = scale * (A[M,K] @ B[N,K]^T) + bias
//   Tile 128xBN, BK=64, 256 threads (4 waves), XOR-swizzled LDS (conflict-free)
//   BIAS: 0 none, 1 bias[col], 2 bias[row]
//   SWZ: 1 = 1-D grid, z = bid % nz (XCD binding), GROUP_M=4 tile order
//   EXP: 1 = write exp(acc*scale), atomic per-column sums into colsum[bz*N+col]
//   CVT bit0/bit1: A/B operand is f32 -> ASYNC-staged as f32 LDS tile (32 KB),
//       converted to bf16 on the LDS->fragment read (R6 lesson: sync staging
//       serializes; async f32 staging keeps the global_load_lds pipe).
//   CSDIV: epilogue divides by colsum[bz*N+col] (softmax normalizer fold)
// ---------------------------------------------------------------------------
template <typename OutT, int BIAS, int BN, int SWZ = 0, int EXP = 0, int CVT = 0,
          int CSDIV = 0>
__global__ __launch_bounds__(256) void gemm_nt(
    const void* __restrict__ Av, const void* __restrict__ Bv,
    OutT* __restrict__ C, const float* __restrict__ bias,
    float* __restrict__ colsum,
    int M, int N, int K,
    long long sA, long long sB, long long sC,
    float scale, int nz, int npn)
{
    constexpr int NF = BN / 32;              // B frags per wave (n-dir)
    constexpr bool AF = (CVT & 1) != 0, BF = (CVT & 2) != 0;
    __shared__ __align__(16) char AsRaw[AF ? 128 * 64 * 4 : 128 * 64 * 2];
    __shared__ __align__(16) char BsRaw[BF ? BN * 64 * 4 : BN * 64 * 2];
    bf16*  As  = (bf16*)AsRaw;   float* Asf = (float*)AsRaw;
    bf16*  Bs  = (bf16*)BsRaw;   float* Bsf = (float*)BsRaw;

    int bz, m0, n0;
    if constexpr (SWZ) {
        const int bid = blockIdx.x;
        bz = bid % nz;                        // bind batch -> XCD (round-robin)
        const int t0 = bid / nz;
        const int grp = t0 / (4 * npn);       // GROUP_M = 4
        m0 = (grp * 4 + (t0 % 4)) * 128;
        n0 = ((t0 / 4) % npn) * BN;
    } else {
        bz = blockIdx.z;
        m0 = blockIdx.y * 128;
        n0 = blockIdx.x * BN;
    }
    C += sC * bz;

    const bf16*  A16 = nullptr; const float* A32 = nullptr;
    const bf16*  B16 = nullptr; const float* B32 = nullptr;
    if constexpr (AF) A32 = (const float*)Av + sA * bz;
    else              A16 = (const bf16*)Av + sA * bz;
    if constexpr (BF) B32 = (const float*)Bv + sB * bz;
    else              B16 = (const bf16*)Bv + sB * bz;

    const int t = threadIdx.x;
    const int lane = t & 63;
    const int w = t >> 6;                    // wave id 0..3
    const int wm = (w >> 1) * 64;            // wave row offset
    const int wn = (w & 1) * (BN / 2);       // wave col offset

    f32x4 acc[4][NF] = {};

    // bf16 staging: idx = c*256+t -> row = idx>>3, swizzle XOR-(row&7) on 8 chunks
    const int trow = t >> 3;
    const int tcol = (t & 7) ^ (trow & 7);
    // f32 staging: idx = c*256+t -> row = c*16 + (t>>4), swizzle XOR-(t>>4) on 16 chunks
    const int t16r = t >> 4;
    const int t16c = (t & 15) ^ t16r;
    char* stA = (char*)AsRaw + (size_t)w * 1024;   // + c*4096 per call (wave-uniform)
    char* stB = (char*)BsRaw + (size_t)w * 1024;

    for (int k0 = 0; k0 < K; k0 += 64) {
        __syncthreads();   // protect LDS while other waves still compute
        if constexpr (AF) {
            const float* a_src = A32 + (long long)(m0 + t16r) * K + k0 + t16c * 4;
#pragma unroll
            for (int c = 0; c < 8; ++c)
                async_cp16(a_src + (long long)(c * 16) * K, stA + c * 4096);
        } else {
            const bf16* a_src = A16 + (long long)(m0 + trow) * K + k0 + tcol * 8;
#pragma unroll
            for (int c = 0; c < 4; ++c)
                async_cp16(a_src + (long long)(c * 32) * K, stA + c * 4096);
        }
        if constexpr (BF) {
            const float* b_src = B32 + (long long)(n0 + t16r) * K + k0 + t16c * 4;
#pragma unroll
            for (int c = 0; c < BN / 16; ++c)
                async_cp16(b_src + (long long)(c * 16) * K, stB + c * 4096);
        } else {
            const bf16* b_src = B16 + (long long)(n0 + trow) * K + k0 + tcol * 8;
#pragma unroll
            for (int c = 0; c < NF; ++c)
                async_cp16(b_src + (long long)(c * 32) * K, stB + c * 4096);
        }
        __syncthreads();   // vmcnt drain before s_barrier

        const int rl = lane & 15;
        const int quad = lane >> 4;
        const int sw = rl & 7;
#pragma unroll
        for (int kk = 0; kk < 64; kk += 32) {
            const int c8 = (kk >> 3) + quad;          // bf16 logical chunk (8B units)
            const int ko = ((c8 ^ sw) << 3);          // bf16 physical elem offset
            const int l0 = (kk >> 2) + quad * 2;      // f32 logical chunk (16B units)
            s16x8 af[4], bfr[NF];
#pragma unroll
            for (int i = 0; i < 4; ++i) {
                if constexpr (AF) {
                    const float* rp = Asf + (size_t)(wm + i * 16 + rl) * 64;
                    float4 f0 = *(const float4*)(rp + ((l0 ^ rl) << 2));
                    float4 f1 = *(const float4*)(rp + (((l0 + 1) ^ rl) << 2));
                    af[i] = pack8(f0, f1);
                } else {
                    af[i] = *(const s16x8*)(As + (wm + i * 16 + rl) * 64 + ko);
                }
            }
#pragma unroll
            for (int j = 0; j < NF; ++j) {
                if constexpr (BF) {
                    const float* rp = Bsf + (size_t)(wn + j * 16 + rl) * 64;
                    float4 f0 = *(const float4*)(rp + ((l0 ^ rl) << 2));
                    float4 f1 = *(const float4*)(rp + (((l0 + 1) ^ rl) << 2));
                    bfr[j] = pack8(f0, f1);
                } else {
                    bfr[j] = *(const s16x8*)(Bs + (wn + j * 16 + rl) * 64 + ko);
                }
            }
#pragma unroll
            for (int i = 0; i < 4; ++i)
#pragma unroll
                for (int j = 0; j < NF; ++j)
                    acc[i][j] = __builtin_amdgcn_mfma_f32_16x16x32_bf16(
                        af[i], bfr[j], acc[i][j], 0, 0, 0);
        }
    }

    // epilogue: D row = (lane>>4)*4 + r, col = lane&15  (verified m89/m91)
    const int cl = lane & 15;
    const int rquad = (lane >> 4) << 2;
#pragma unroll
    for (int tn = 0; tn < NF; ++tn) {
        const int col = n0 + wn + tn * 16 + cl;
        if constexpr (EXP) {
            float csum = 0.f;
#pragma unroll
            for (int tm = 0; tm < 4; ++tm) {
#pragma unroll
                for (int r = 0; r < 4; ++r) {
                    const int row = m0 + wm + tm * 16 + rquad + r;
                    float v = __expf(acc[tm][tn][r] * scale);
                    csum += v;
                    storeC(C + (long long)row * N + col, v);
                }
            }
            csum += __shfl_xor(csum, 16);
            csum += __shfl_xor(csum, 32);
            if ((lane >> 4) == 0)
                atomicAdd(&colsum[(long long)bz * N + col], csum);
        } else {
            float bcol = 0.f;
            if constexpr (BIAS == 1) bcol = bias[col];
            float inv = 1.0f;
            if constexpr (CSDIV) inv = 1.0f / colsum[(long long)bz * N + col];
#pragma unroll
            for (int tm = 0; tm < 4; ++tm) {
#pragma unroll
                for (int r = 0; r < 4; ++r) {
                    const int row = m0 + wm + tm * 16 + rquad + r;
                    float v = acc[tm][tn][r] * scale;
                    if constexpr (BIAS == 1) v += bcol;
                    if constexpr (BIAS == 2) v += bias[row];
                    if constexpr (CSDIV) v *= inv;
                    storeC(C + (long long)row * N + col, v);
                }
            }
        }
    }
}

// ---------------------------------------------------------------------------
extern "C" void kernel_launch(void* const* d_in, const int* in_sizes, int n_in,
                              void* d_out, int out_size, void* d_ws, size_t ws_size,
                              hipStream_t stream)
{
    constexpr int Bb = 8, NK = 2048, NQ = 2048, D = 256, H = 1024;
    const float scale = 0.03125f;   // 1/sqrt(1024)
    constexpr size_t E1  = (size_t)Bb * NK * H;   // 16,777,216 elems (33.55 MB bf16)
    constexpr size_t ES  = (size_t)NK * NQ;       // 4,194,304 elems per batch
    constexpr size_t WSZ = (size_t)H * D;         // 262,144 elems
    constexpr size_t MISC = 4 * WSZ * 2 + (size_t)8 * NK * 4 + 256;

    const float* KEY   = (const float*)d_in[0];
    const float* VALUE = (const float*)d_in[1];
    const float* QUERY = (const float*)d_in[2];
    const float* Wk_w  = (const float*)d_in[3];
    const float* Wk_b  = (const float*)d_in[4];
    const float* Wq_w  = (const float*)d_in[5];
    const float* Wq_b  = (const float*)d_in[6];
    const float* Wv_w  = (const float*)d_in[7];
    const float* Wv_b  = (const float*)d_in[8];
    const float* lin_w = (const float*)d_in[9];
    const float* lin_b = (const float*)d_in[10];
    float* out = (float*)d_out;

    // group size: largest g whose workspace fits (deterministic across calls)
    auto need = [&](int g) -> size_t {
        return 3 * E1 * 2 + (g < 8 ? E1 * 2 : 0) + (size_t)g * ES * 2 + MISC;
    };
    const int g = (ws_size >= need(8)) ? 8 : (ws_size >= need(4)) ? 4 : 2;

    char* ws = (char*)d_ws;
    bf16* Kp   = (bf16*)ws;  ws += E1 * 2;
    bf16* Qp   = (bf16*)ws;  ws += E1 * 2;
    bf16* VpT  = (bf16*)ws;  ws += E1 * 2;                 // [b][h][i], normalized
    bf16* ctx  = Kp;                                       // g==8: alias dead Kp
    if (g < 8) { ctx = (bf16*)ws; ws += E1 * 2; }
    bf16* Sg   = (bf16*)ws;  ws += (size_t)g * ES * 2;     // STexp[k,i], bf16
    float* csm = (float*)ws; ws += (size_t)8 * NK * 4;     // column sums (global batch)
    bf16* Wkb  = (bf16*)ws;  ws += WSZ * 2;
    bf16* Wqb  = (bf16*)ws;  ws += WSZ * 2;
    bf16* Wvb  = (bf16*)ws;  ws += WSZ * 2;
    bf16* linb = (bf16*)ws;  ws += WSZ * 2;

    dim3 blk(256);

    // 0: weights f32 -> bf16 (4 tensors) + zero csm (grid.y == 4)
    {
        const int n4w = (int)(WSZ / 4);
        cvt4z_kernel<<<dim3(n4w / 256, 5), blk, 0, stream>>>(
            Wk_w, Wq_w, Wv_w, lin_w, Wkb, n4w, csm, 8 * NK / 4);
    }

    // 1,2: projections K,Q  (M=16384, N=H, K=D) + col bias; A async-staged f32
    gemm_nt<bf16, 1, 128, 0, 0, 1><<<dim3(H / 128, Bb * NK / 128, 1), blk, 0, stream>>>(
        KEY, Wkb, Kp, Wk_b, nullptr, Bb * NK, H, D, 0, 0, 0, 1.0f, 1, 1);
    gemm_nt<bf16, 1, 128, 0, 0, 1><<<dim3(H / 128, Bb * NQ / 128, 1), blk, 0, stream>>>(
        QUERY, Wqb, Qp, Wq_b, nullptr, Bb * NQ, H, D, 0, 0, 0, 1.0f, 1, 1);

    // 3..5 per group of g batches
    for (int b0 = 0; b0 < Bb; b0 += g) {
        // 3: STexp[k,i] = exp(scale * Qp[b] @ Kp[b]^T), colsum[b,i] += col sums
        gemm_nt<bf16, 0, 128, 1, 1, 0><<<dim3(g * (NQ / 128) * (NK / 128)), blk, 0, stream>>>(
            Qp + (size_t)b0 * NQ * H, Kp + (size_t)b0 * NK * H, Sg, nullptr,
            csm + (size_t)b0 * NK,
            NQ, NK, H,
            (long long)NQ * H, (long long)NK * H, (long long)NQ * NK, scale,
            g, NK / 128);
        // 4: VpT[b,h,i] = (Wv_w @ VALUE[b]^T + Wv_b[row]) / colsum[b,i]
        //    (B async-staged f32; normalizer folded into epilogue)
        gemm_nt<bf16, 2, 128, 0, 0, 2, 1><<<dim3(NK / 128, H / 128, g), blk, 0, stream>>>(
            Wvb, VALUE + (size_t)b0 * NK * D, VpT + (size_t)b0 * H * NK, Wv_b,
            csm + (size_t)b0 * NK,
            H, NK, D,
            0, (long long)NK * D, (long long)H * NK, 1.0f, 1, 1);
        // 5: ctx[k,h] = STexp @ VpT^T   (M=NQ, N=H, K=NK, swizzled)
        gemm_nt<bf16, 0, 128, 1, 0, 0><<<dim3(g * (NQ / 128) * (H / 128)), blk, 0, stream>>>(
            Sg, VpT + (size_t)b0 * H * NK, ctx + (size_t)b0 * NQ * H, nullptr, nullptr,
            NQ, H, NK,
            (long long)NQ * NK, (long long)H * NK, (long long)NQ * H, 1.0f,
            g, H / 128);
    }

    // 6: out = ctx @ lin_w^T + lin_b   (M=16384, N=D, K=H) -> f32 d_out, BN=64
    gemm_nt<float, 1, 64, 0, 0, 0><<<dim3(D / 64, Bb * NQ / 128, 1), blk, 0, stream>>>(
        ctx, linb, out, lin_b, nullptr, Bb * NQ, D, H, 0, 0, 0, 1.0f, 1, 1);
}

// Round 8
// 314.918 us; speedup vs baseline: 1.2298x; 1.1491x over previous
//
#include <hip/hip_runtime.h>
#include <hip/hip_bf16.h>

using bf16 = __hip_bfloat16;
typedef __attribute__((ext_vector_type(8))) short s16x8;   // 8 bf16 = 4 VGPRs
typedef __attribute__((ext_vector_type(4))) float f32x4;

// ---- async global->LDS 16B copy (wave-uniform LDS base + lane*16) ----
__device__ __forceinline__ void async_cp16(const void* g, void* lds) {
    __builtin_amdgcn_global_load_lds(
        (const __attribute__((address_space(1))) unsigned int*)g,
        (__attribute__((address_space(3))) unsigned int*)lds,
        16, 0, 0);
}

__device__ __forceinline__ void storeC(float* p, float v) { *p = v; }
__device__ __forceinline__ void storeC(bf16* p, float v) { *p = __float2bfloat16(v); }

// pack 8 f32 -> s16x8 bf16 fragment
__device__ __forceinline__ s16x8 pack8(float4 a, float4 b) {
    union { bf16 h[8]; s16x8 v; } o;
    o.h[0] = __float2bfloat16(a.x); o.h[1] = __float2bfloat16(a.y);
    o.h[2] = __float2bfloat16(a.z); o.h[3] = __float2bfloat16(a.w);
    o.h[4] = __float2bfloat16(b.x); o.h[5] = __float2bfloat16(b.y);
    o.h[6] = __float2bfloat16(b.z); o.h[7] = __float2bfloat16(b.w);
    return o.v;
}

// ---------------------------------------------------------------------------
// prep: y=0 transpose Wk_w[1024,256]->WkT[384,1024] rows 0..255, row256=Wk_b,
//            rows 257..383 = 0
//       y=1 transpose Wq_w -> WqT[256,1024]
//       y=2 straight cvt Wv_w -> Wvb       y=3 straight cvt lin_w -> linb
//       y=4 zero csm (16384 f32)
// grid (256, 5) x 256 threads
// ---------------------------------------------------------------------------
__global__ __launch_bounds__(256) void prep_kernel(
    const float* __restrict__ Wk_w, const float* __restrict__ Wk_b,
    const float* __restrict__ Wq_w, const float* __restrict__ Wv_w,
    const float* __restrict__ lin_w,
    bf16* __restrict__ WkT, bf16* __restrict__ WqT,
    bf16* __restrict__ Wvb, bf16* __restrict__ linb,
    float* __restrict__ csm)
{
    const int t = threadIdx.x, b = blockIdx.x, y = blockIdx.y;
    if (y <= 1) {
        const float* src = y ? Wq_w : Wk_w;
        bf16* dst = y ? WqT : WkT;
        if (b < 64) {                       // 64x64 transpose tiles (16 x 4)
            __shared__ float T[64][65];
            const int h0 = (b & 15) * 64, d0 = (b >> 4) * 64;
            const int r = t >> 2, cg = t & 3;
            const float* sp = src + (h0 + r) * 256 + d0 + cg * 16;
#pragma unroll
            for (int c4 = 0; c4 < 4; ++c4) {
                float4 v = *(const float4*)(sp + c4 * 4);
                const int cb = cg * 16 + c4 * 4;
                T[cb + 0][r] = v.x; T[cb + 1][r] = v.y;
                T[cb + 2][r] = v.z; T[cb + 3][r] = v.w;
            }
            __syncthreads();
            union { bf16 h[16]; uint4 u[2]; } o;
#pragma unroll
            for (int j = 0; j < 16; ++j) o.h[j] = __float2bfloat16(T[r][cg * 16 + j]);
            uint4* dp = (uint4*)(dst + (size_t)(d0 + r) * 1024 + h0 + cg * 16);
            dp[0] = o.u[0]; dp[1] = o.u[1];
        } else if (y == 0) {
            if (b < 68) {                   // row 256 = Wk_b
                const int i = (b - 64) * 256 + t;
                WkT[256 * 1024 + i] = __float2bfloat16(Wk_b[i]);
            } else if (b < 132) {           // rows 257..383 = 0 (127*1024 bf16)
                const int i = (b - 68) * 256 + t;
                if (i < 127 * 1024 / 8)
                    ((uint4*)(WkT + 257 * 1024))[i] = uint4{0, 0, 0, 0};
            }
        }
    } else if (y <= 3) {
        const float* src = (y == 2) ? Wv_w : lin_w;
        bf16* dst = (y == 2) ? Wvb : linb;
        const int i = b * 256 + t;          // 65536 float4 groups
        float4 v = ((const float4*)src)[i];
        union { bf16 h[4]; uint2 u; } o;
        o.h[0] = __float2bfloat16(v.x); o.h[1] = __float2bfloat16(v.y);
        o.h[2] = __float2bfloat16(v.z); o.h[3] = __float2bfloat16(v.w);
        ((uint2*)dst)[i] = o.u;
    } else {
        const int i = b * 256 + t;
        if (i < 4096) ((float4*)csm)[i] = float4{0.f, 0.f, 0.f, 0.f};
    }
}

// ---------------------------------------------------------------------------
// NT GEMM: C[M,N] = scale * (A[M,K] @ B[N,K]^T) + bias
//   Tile 128xBN, BK=64, 256 threads (4 waves), XOR-swizzled LDS (conflict-free)
//   BIAS: 0 none, 1 bias[col*bstride], 2 bias[row]
//   SWZ: 1 = 1-D grid, z = bid % nz (XCD binding), GROUP_M=4 tile order
//   EXP: 1 = write exp(acc*scale), atomic per-column sums into colsum[bz*N+col]
//   CVT bit0/bit1: A/B operand is f32 -> ASYNC-staged f32 LDS tile, converted
//       to bf16 on LDS->fragment read (R6 lesson: sync staging serializes)
//   CSDIV: epilogue divides by colsum[bz*N+col]
//   ldA/ldB: row strides (elements) of A and B
// ---------------------------------------------------------------------------
template <typename OutT, int BIAS, int BN, int SWZ = 0, int EXP = 0, int CVT = 0,
          int CSDIV = 0>
__global__ __launch_bounds__(256) void gemm_nt(
    const void* __restrict__ Av, const void* __restrict__ Bv,
    OutT* __restrict__ C, const float* __restrict__ bias, int bstride,
    float* __restrict__ colsum,
    int M, int N, int K, int ldA, int ldB,
    long long sA, long long sB, long long sC,
    float scale, int nz, int npn)
{
    constexpr int NF = BN / 32;              // B frags per wave (n-dir)
    constexpr bool AF = (CVT & 1) != 0, BF = (CVT & 2) != 0;
    __shared__ __align__(16) char AsRaw[AF ? 128 * 64 * 4 : 128 * 64 * 2];
    __shared__ __align__(16) char BsRaw[BF ? BN * 64 * 4 : BN * 64 * 2];
    bf16*  As  = (bf16*)AsRaw;   float* Asf = (float*)AsRaw;
    bf16*  Bs  = (bf16*)BsRaw;   float* Bsf = (float*)BsRaw;

    int bz, m0, n0;
    if constexpr (SWZ) {
        const int bid = blockIdx.x;
        bz = bid % nz;                        // bind batch -> XCD (round-robin)
        const int t0 = bid / nz;
        const int grp = t0 / (4 * npn);       // GROUP_M = 4
        m0 = (grp * 4 + (t0 % 4)) * 128;
        n0 = ((t0 / 4) % npn) * BN;
    } else {
        bz = blockIdx.z;
        m0 = blockIdx.y * 128;
        n0 = blockIdx.x * BN;
    }
    C += sC * bz;

    const bf16*  A16 = nullptr; const float* A32 = nullptr;
    const bf16*  B16 = nullptr; const float* B32 = nullptr;
    if constexpr (AF) A32 = (const float*)Av + sA * bz;
    else              A16 = (const bf16*)Av + sA * bz;
    if constexpr (BF) B32 = (const float*)Bv + sB * bz;
    else              B16 = (const bf16*)Bv + sB * bz;

    const int t = threadIdx.x;
    const int lane = t & 63;
    const int w = t >> 6;                    // wave id 0..3
    const int wm = (w >> 1) * 64;            // wave row offset
    const int wn = (w & 1) * (BN / 2);       // wave col offset

    f32x4 acc[4][NF] = {};

    // bf16 staging: idx = c*256+t -> row = idx>>3, swizzle XOR-(row&7) on 8 chunks
    const int trow = t >> 3;
    const int tcol = (t & 7) ^ (trow & 7);
    // f32 staging: idx = c*256+t -> row = c*16 + (t>>4), swizzle XOR-(t>>4) on 16
    const int t16r = t >> 4;
    const int t16c = (t & 15) ^ t16r;
    char* stA = (char*)AsRaw + (size_t)w * 1024;   // + c*4096 (wave-uniform)
    char* stB = (char*)BsRaw + (size_t)w * 1024;

    for (int k0 = 0; k0 < K; k0 += 64) {
        __syncthreads();   // protect LDS while other waves still compute
        if constexpr (AF) {
            const float* a_src = A32 + (long long)(m0 + t16r) * ldA + k0 + t16c * 4;
#pragma unroll
            for (int c = 0; c < 8; ++c)
                async_cp16(a_src + (long long)(c * 16) * ldA, stA + c * 4096);
        } else {
            const bf16* a_src = A16 + (long long)(m0 + trow) * ldA + k0 + tcol * 8;
#pragma unroll
            for (int c = 0; c < 4; ++c)
                async_cp16(a_src + (long long)(c * 32) * ldA, stA + c * 4096);
        }
        if constexpr (BF) {
            const float* b_src = B32 + (long long)(n0 + t16r) * ldB + k0 + t16c * 4;
#pragma unroll
            for (int c = 0; c < BN / 16; ++c)
                async_cp16(b_src + (long long)(c * 16) * ldB, stB + c * 4096);
        } else {
            const bf16* b_src = B16 + (long long)(n0 + trow) * ldB + k0 + tcol * 8;
#pragma unroll
            for (int c = 0; c < NF; ++c)
                async_cp16(b_src + (long long)(c * 32) * ldB, stB + c * 4096);
        }
        __syncthreads();   // vmcnt drain before s_barrier

        const int rl = lane & 15;
        const int quad = lane >> 4;
        const int sw = rl & 7;
#pragma unroll
        for (int kk = 0; kk < 64; kk += 32) {
            const int c8 = (kk >> 3) + quad;          // bf16 logical chunk (8B)
            const int ko = ((c8 ^ sw) << 3);          // bf16 physical elem offset
            const int l0 = (kk >> 2) + quad * 2;      // f32 logical chunk (16B)
            s16x8 af[4], bfr[NF];
#pragma unroll
            for (int i = 0; i < 4; ++i) {
                if constexpr (AF) {
                    const float* rp = Asf + (size_t)(wm + i * 16 + rl) * 64;
                    float4 f0 = *(const float4*)(rp + ((l0 ^ rl) << 2));
                    float4 f1 = *(const float4*)(rp + (((l0 + 1) ^ rl) << 2));
                    af[i] = pack8(f0, f1);
                } else {
                    af[i] = *(const s16x8*)(As + (wm + i * 16 + rl) * 64 + ko);
                }
            }
#pragma unroll
            for (int j = 0; j < NF; ++j) {
                if constexpr (BF) {
                    const float* rp = Bsf + (size_t)(wn + j * 16 + rl) * 64;
                    float4 f0 = *(const float4*)(rp + ((l0 ^ rl) << 2));
                    float4 f1 = *(const float4*)(rp + (((l0 + 1) ^ rl) << 2));
                    bfr[j] = pack8(f0, f1);
                } else {
                    bfr[j] = *(const s16x8*)(Bs + (wn + j * 16 + rl) * 64 + ko);
                }
            }
#pragma unroll
            for (int i = 0; i < 4; ++i)
#pragma unroll
                for (int j = 0; j < NF; ++j)
                    acc[i][j] = __builtin_amdgcn_mfma_f32_16x16x32_bf16(
                        af[i], bfr[j], acc[i][j], 0, 0, 0);
        }
    }

    // epilogue: D row = (lane>>4)*4 + r, col = lane&15  (verified m89/m91)
    const int cl = lane & 15;
    const int rquad = (lane >> 4) << 2;
#pragma unroll
    for (int tn = 0; tn < NF; ++tn) {
        const int col = n0 + wn + tn * 16 + cl;
        if constexpr (EXP) {
            float csum = 0.f;
#pragma unroll
            for (int tm = 0; tm < 4; ++tm) {
#pragma unroll
                for (int r = 0; r < 4; ++r) {
                    const int row = m0 + wm + tm * 16 + rquad + r;
                    float v = __expf(acc[tm][tn][r] * scale);
                    csum += v;
                    storeC(C + (long long)row * N + col, v);
                }
            }
            csum += __shfl_xor(csum, 16);
            csum += __shfl_xor(csum, 32);
            if ((lane >> 4) == 0)
                atomicAdd(&colsum[(long long)bz * N + col], csum);
        } else {
            float bcol = 0.f;
            if constexpr (BIAS == 1) bcol = bias[(long long)col * bstride];
            float inv = 1.0f;
            if constexpr (CSDIV) inv = 1.0f / colsum[(long long)bz * N + col];
#pragma unroll
            for (int tm = 0; tm < 4; ++tm) {
#pragma unroll
                for (int r = 0; r < 4; ++r) {
                    const int row = m0 + wm + tm * 16 + rquad + r;
                    float v = acc[tm][tn][r] * scale;
                    if constexpr (BIAS == 1) v += bcol;
                    if constexpr (BIAS == 2) v += bias[row];
                    if constexpr (CSDIV) v *= inv;
                    storeC(C + (long long)row * N + col, v);
                }
            }
        }
    }
}

// ---------------------------------------------------------------------------
extern "C" void kernel_launch(void* const* d_in, const int* in_sizes, int n_in,
                              void* d_out, int out_size, void* d_ws, size_t ws_size,
                              hipStream_t stream)
{
    constexpr int Bb = 8, NK = 2048, NQ = 2048, D = 256, H = 1024;
    const float scale = 0.03125f;   // 1/sqrt(1024)
    constexpr size_t E1  = (size_t)Bb * NK * H;   // 16,777,216 (33.55 MB bf16)
    constexpr size_t ES  = (size_t)NK * NQ;       // per-batch scores
    constexpr size_t ET  = (size_t)Bb * NK * D;   // T' elems (8.39 MB bf16)
    constexpr size_t FIX = 2 * E1 * 2 + ET * 2 + 256 * 384 * 4
                         + (384 + 256 + 256 + 256) * 1024 * 2  // wait: weights
                         + (size_t)8 * NK * 4 + 1024;

    const float* KEY   = (const float*)d_in[0];
    const float* VALUE = (const float*)d_in[1];
    const float* QUERY = (const float*)d_in[2];
    const float* Wk_w  = (const float*)d_in[3];
    const float* Wk_b  = (const float*)d_in[4];
    const float* Wq_w  = (const float*)d_in[5];
    const float* Wq_b  = (const float*)d_in[6];   // cancels in softmax (unused)
    const float* Wv_w  = (const float*)d_in[7];
    const float* Wv_b  = (const float*)d_in[8];
    const float* lin_w = (const float*)d_in[9];
    const float* lin_b = (const float*)d_in[10];
    float* out = (float*)d_out;
    (void)Wq_b; (void)in_sizes; (void)n_in; (void)out_size;

    auto need = [&](int g) -> size_t { return FIX + (size_t)g * ES * 2; };
    const int g = (ws_size >= need(8)) ? 8 : (ws_size >= need(4)) ? 4 : 2;

    char* ws = (char*)d_ws;
    bf16* VpT  = (bf16*)ws;  ws += E1 * 2;                 // [b][h][i], normalized
    bf16* ctx  = (bf16*)ws;  ws += E1 * 2;                 // [b][k][h]
    bf16* Sg   = (bf16*)ws;  ws += (size_t)g * ES * 2;     // STexp[k,i]
    bf16* Tp   = (bf16*)ws;  ws += ET * 2;                 // T' = KEY@G + vq
    float* C1  = (float*)ws; ws += (size_t)256 * 384 * 4;  // Gt | vq col
    bf16* WkT  = (bf16*)ws;  ws += (size_t)384 * 1024 * 2; // [Wk^T; Wk_b; 0]
    bf16* WqT  = (bf16*)ws;  ws += (size_t)256 * 1024 * 2;
    bf16* Wvb  = (bf16*)ws;  ws += (size_t)H * D * 2;
    bf16* linb = (bf16*)ws;  ws += (size_t)D * H * 2;
    float* csm = (float*)ws; ws += (size_t)8 * NK * 4;     // column sums

    dim3 blk(256);

    // 0: weight transposes/cvt + pad row + zero csm (one launch)
    prep_kernel<<<dim3(256, 5), blk, 0, stream>>>(
        Wk_w, Wk_b, Wq_w, Wv_w, lin_w, WkT, WqT, Wvb, linb, csm);

    // 1: C1[e, n] = WqT[e,:] . WkT[n,:]  (M=256, N=384, K=1024) -> f32
    //    C1[e, 0:256] = G^T[e, dk],  C1[e, 256] = vq[e]
    gemm_nt<float, 0, 128><<<dim3(3, 2, 1), blk, 0, stream>>>(
        WqT, WkT, C1, nullptr, 1, nullptr, 256, 384, 1024, 1024, 1024,
        0, 0, 0, 1.0f, 1, 1);

    // 2: T'[i, e] = KEY[i,:] . C1[e, 0:256] + vq[e]   (both operands f32)
    gemm_nt<bf16, 1, 128, 0, 0, 3><<<dim3(2, 128, 1), blk, 0, stream>>>(
        KEY, C1, Tp, C1 + 256, 384, nullptr, Bb * NK, D, D, D, 384,
        0, 0, 0, 1.0f, 1, 1);

    // 3..5 per group of g batches
    for (int b0 = 0; b0 < Bb; b0 += g) {
        // 3: STexp[k,i] = exp(scale * QUERY[k,:].T'[i,:]), colsum[i] += sums
        gemm_nt<bf16, 0, 128, 1, 1, 1><<<dim3(g * (NQ / 128) * (NK / 128)), blk, 0, stream>>>(
            QUERY + (size_t)b0 * NQ * D, Tp + (size_t)b0 * NK * D, Sg,
            nullptr, 1, csm + (size_t)b0 * NK,
            NQ, NK, D, D, D,
            (long long)NQ * D, (long long)NK * D, (long long)NQ * NK, scale,
            g, NK / 128);
        // 4: VpT[b,h,i] = (Wv_w @ VALUE[b]^T + Wv_b[row]) / colsum[b,i]
        gemm_nt<bf16, 2, 128, 0, 0, 2, 1><<<dim3(NK / 128, H / 128, g), blk, 0, stream>>>(
            Wvb, VALUE + (size_t)b0 * NK * D, VpT + (size_t)b0 * H * NK,
            Wv_b, 1, csm + (size_t)b0 * NK,
            H, NK, D, D, D,
            0, (long long)NK * D, (long long)H * NK, 1.0f, 1, 1);
        // 5: ctx[k,h] = STexp @ VpT^T   (M=NQ, N=H, K=NK, swizzled)
        gemm_nt<bf16, 0, 128, 1><<<dim3(g * (NQ / 128) * (H / 128)), blk, 0, stream>>>(
            Sg, VpT + (size_t)b0 * H * NK, ctx + (size_t)b0 * NQ * H,
            nullptr, 1, nullptr,
            NQ, H, NK, NK, NK,
            (long long)NQ * NK, (long long)H * NK, (long long)NQ * H, 1.0f,
            g, H / 128);
    }

    // 6: out = ctx @ lin_w^T + lin_b   (M=16384, N=D, K=H) -> f32, BN=64
    gemm_nt<float, 1, 64><<<dim3(D / 64, Bb * NQ / 128, 1), blk, 0, stream>>>(
        ctx, linb, out, lin_b, 1, nullptr, Bb * NQ, D, H, H, H,
        0, 0, 0, 1.0f, 1, 1);
}

// Round 10
// 228.252 us; speedup vs baseline: 1.6967x; 1.3797x over previous
//
#include <hip/hip_runtime.h>
#include <hip/hip_bf16.h>

using bf16 = __hip_bfloat16;
typedef __attribute__((ext_vector_type(8))) short s16x8;   // 8 bf16 = 4 VGPRs
typedef __attribute__((ext_vector_type(4))) float f32x4;

// ---- async global->LDS 16B copy (wave-uniform LDS base + lane*16) ----
__device__ __forceinline__ void async_cp16(const void* g, void* lds) {
    __builtin_amdgcn_global_load_lds(
        (const __attribute__((address_space(1))) unsigned int*)g,
        (__attribute__((address_space(3))) unsigned int*)lds,
        16, 0, 0);
}

__device__ __forceinline__ void storeC(float* p, float v) { *p = v; }
__device__ __forceinline__ void storeC(bf16* p, float v) { *p = __float2bfloat16(v); }

// pack 8 f32 -> s16x8 bf16 fragment
__device__ __forceinline__ s16x8 pack8(float4 a, float4 b) {
    union { bf16 h[8]; s16x8 v; } o;
    o.h[0] = __float2bfloat16(a.x); o.h[1] = __float2bfloat16(a.y);
    o.h[2] = __float2bfloat16(a.z); o.h[3] = __float2bfloat16(a.w);
    o.h[4] = __float2bfloat16(b.x); o.h[5] = __float2bfloat16(b.y);
    o.h[6] = __float2bfloat16(b.z); o.h[7] = __float2bfloat16(b.w);
    return o.v;
}

// ---------------------------------------------------------------------------
// prep: y=0: WkT[384,1024] = [Wk_w^T ; Wk_b ; 0]
//       y=1: WqT[256,1024] = Wq_w^T
//       y=2: WvT[384,1024] = [Wv_w^T ; Wv_b ; 0]
//       y=3: linb[256,1024] = bf16(lin_w)   y=4: zero csm (16384 f32)
// grid (256, 5) x 256 threads
// ---------------------------------------------------------------------------
__global__ __launch_bounds__(256) void prep_kernel(
    const float* __restrict__ Wk_w, const float* __restrict__ Wk_b,
    const float* __restrict__ Wq_w,
    const float* __restrict__ Wv_w, const float* __restrict__ Wv_b,
    const float* __restrict__ lin_w,
    bf16* __restrict__ WkT, bf16* __restrict__ WqT, bf16* __restrict__ WvT,
    bf16* __restrict__ linb, float* __restrict__ csm)
{
    const int t = threadIdx.x, b = blockIdx.x, y = blockIdx.y;
    if (y <= 2) {
        const float* src = (y == 0) ? Wk_w : (y == 1) ? Wq_w : Wv_w;
        const float* bia = (y == 0) ? Wk_b : Wv_b;
        bf16* dst = (y == 0) ? WkT : (y == 1) ? WqT : WvT;
        if (b < 64) {                       // 64x64 transpose tiles (16 x 4)
            __shared__ float T[64][65];
            const int h0 = (b & 15) * 64, d0 = (b >> 4) * 64;
            const int r = t >> 2, cg = t & 3;
            const float* sp = src + (h0 + r) * 256 + d0 + cg * 16;
#pragma unroll
            for (int c4 = 0; c4 < 4; ++c4) {
                float4 v = *(const float4*)(sp + c4 * 4);
                const int cb = cg * 16 + c4 * 4;
                T[cb + 0][r] = v.x; T[cb + 1][r] = v.y;
                T[cb + 2][r] = v.z; T[cb + 3][r] = v.w;
            }
            __syncthreads();
            union { bf16 h[16]; uint4 u[2]; } o;
#pragma unroll
            for (int j = 0; j < 16; ++j) o.h[j] = __float2bfloat16(T[r][cg * 16 + j]);
            uint4* dp = (uint4*)(dst + (size_t)(d0 + r) * 1024 + h0 + cg * 16);
            dp[0] = o.u[0]; dp[1] = o.u[1];
        } else if (y != 1) {
            if (b < 68) {                   // row 256 = bias
                const int i = (b - 64) * 256 + t;
                dst[256 * 1024 + i] = __float2bfloat16(bia[i]);
            } else if (b < 132) {           // rows 257..383 = 0
                const int i = (b - 68) * 256 + t;
                if (i < 127 * 1024 / 8)
                    ((uint4*)(dst + 257 * 1024))[i] = uint4{0, 0, 0, 0};
            }
        }
    } else if (y == 3) {
        const int i = b * 256 + t;          // 65536 float4 groups
        float4 v = ((const float4*)lin_w)[i];
        union { bf16 h[4]; uint2 u; } o;
        o.h[0] = __float2bfloat16(v.x); o.h[1] = __float2bfloat16(v.y);
        o.h[2] = __float2bfloat16(v.z); o.h[3] = __float2bfloat16(v.w);
        ((uint2*)linb)[i] = o.u;
    } else {
        const int i = b * 256 + t;
        if (i < 4096) ((float4*)csm)[i] = float4{0.f, 0.f, 0.f, 0.f};
    }
}

// ---------------------------------------------------------------------------
// NT GEMM: C[M,N] = scale * (A[M,K] @ B[N,K]^T) + bias
//   Tile 128xBN, BK=64, 256 threads (4 waves), XOR-swizzled LDS (conflict-free)
//   BIAS: 0 none, 1 bias[col*bstride], 2 bias[row*bstride]
//   SWZ: 1 = 1-D grid, z = bid % nz (XCD binding), GROUP_M=4 tile order
//   EXP: 1 = write exp(acc*scale), atomic col sums into colsum[bz*N+col]
//   CVT bit0/bit1: A/B is f32 -> ASYNC-staged f32 LDS tile, converted on read
//   CSDIV: 1 = divide by colsum[bz*N+col], 2 = divide by colsum[bz*M+row]
// ---------------------------------------------------------------------------
template <typename OutT, int BIAS, int BN, int SWZ = 0, int EXP = 0, int CVT = 0,
          int CSDIV = 0>
__global__ __launch_bounds__(256) void gemm_nt(
    const void* __restrict__ Av, const void* __restrict__ Bv,
    OutT* __restrict__ C, const float* __restrict__ bias, int bstride,
    float* __restrict__ colsum,
    int M, int N, int K, int ldA, int ldB,
    long long sA, long long sB, long long sC,
    float scale, int nz, int npn)
{
    constexpr int NF = BN / 32;              // B frags per wave (n-dir)
    constexpr bool AF = (CVT & 1) != 0, BF = (CVT & 2) != 0;
    __shared__ __align__(16) char AsRaw[AF ? 128 * 64 * 4 : 128 * 64 * 2];
    __shared__ __align__(16) char BsRaw[BF ? BN * 64 * 4 : BN * 64 * 2];
    bf16*  As  = (bf16*)AsRaw;   float* Asf = (float*)AsRaw;
    bf16*  Bs  = (bf16*)BsRaw;   float* Bsf = (float*)BsRaw;

    int bz, m0, n0;
    if constexpr (SWZ) {
        const int bid = blockIdx.x;
        bz = bid % nz;                        // bind batch -> XCD (round-robin)
        const int t0 = bid / nz;
        const int grp = t0 / (4 * npn);       // GROUP_M = 4
        m0 = (grp * 4 + (t0 % 4)) * 128;
        n0 = ((t0 / 4) % npn) * BN;
    } else {
        bz = blockIdx.z;
        m0 = blockIdx.y * 128;
        n0 = blockIdx.x * BN;
    }
    C += sC * bz;

    const bf16*  A16 = nullptr; const float* A32 = nullptr;
    const bf16*  B16 = nullptr; const float* B32 = nullptr;
    if constexpr (AF) A32 = (const float*)Av + sA * bz;
    else              A16 = (const bf16*)Av + sA * bz;
    if constexpr (BF) B32 = (const float*)Bv + sB * bz;
    else              B16 = (const bf16*)Bv + sB * bz;

    const int t = threadIdx.x;
    const int lane = t & 63;
    const int w = t >> 6;                    // wave id 0..3
    const int wm = (w >> 1) * 64;            // wave row offset
    const int wn = (w & 1) * (BN / 2);       // wave col offset

    f32x4 acc[4][NF] = {};

    // bf16 staging: idx = c*256+t -> row = idx>>3, swizzle XOR-(row&7) on 8 chunks
    const int trow = t >> 3;
    const int tcol = (t & 7) ^ (trow & 7);
    // f32 staging: idx = c*256+t -> row = c*16 + (t>>4), swizzle XOR-(t>>4) on 16
    const int t16r = t >> 4;
    const int t16c = (t & 15) ^ t16r;
    char* stA = (char*)AsRaw + (size_t)w * 1024;   // + c*4096 (wave-uniform)
    char* stB = (char*)BsRaw + (size_t)w * 1024;

    for (int k0 = 0; k0 < K; k0 += 64) {
        __syncthreads();   // protect LDS while other waves still compute
        if constexpr (AF) {
            const float* a_src = A32 + (long long)(m0 + t16r) * ldA + k0 + t16c * 4;
#pragma unroll
            for (int c = 0; c < 8; ++c)
                async_cp16(a_src + (long long)(c * 16) * ldA, stA + c * 4096);
        } else {
            const bf16* a_src = A16 + (long long)(m0 + trow) * ldA + k0 + tcol * 8;
#pragma unroll
            for (int c = 0; c < 4; ++c)
                async_cp16(a_src + (long long)(c * 32) * ldA, stA + c * 4096);
        }
        if constexpr (BF) {
            const float* b_src = B32 + (long long)(n0 + t16r) * ldB + k0 + t16c * 4;
#pragma unroll
            for (int c = 0; c < BN / 16; ++c)
                async_cp16(b_src + (long long)(c * 16) * ldB, stB + c * 4096);
        } else {
            const bf16* b_src = B16 + (long long)(n0 + trow) * ldB + k0 + tcol * 8;
#pragma unroll
            for (int c = 0; c < NF; ++c)
                async_cp16(b_src + (long long)(c * 32) * ldB, stB + c * 4096);
        }
        __syncthreads();   // vmcnt drain before s_barrier

        const int rl = lane & 15;
        const int quad = lane >> 4;
        const int sw = rl & 7;
#pragma unroll
        for (int kk = 0; kk < 64; kk += 32) {
            const int c8 = (kk >> 3) + quad;          // bf16 logical chunk (8B)
            const int ko = ((c8 ^ sw) << 3);          // bf16 physical elem offset
            const int l0 = (kk >> 2) + quad * 2;      // f32 logical chunk (16B)
            s16x8 af[4], bfr[NF];
#pragma unroll
            for (int i = 0; i < 4; ++i) {
                if constexpr (AF) {
                    const float* rp = Asf + (size_t)(wm + i * 16 + rl) * 64;
                    float4 f0 = *(const float4*)(rp + ((l0 ^ rl) << 2));
                    float4 f1 = *(const float4*)(rp + (((l0 + 1) ^ rl) << 2));
                    af[i] = pack8(f0, f1);
                } else {
                    af[i] = *(const s16x8*)(As + (wm + i * 16 + rl) * 64 + ko);
                }
            }
#pragma unroll
            for (int j = 0; j < NF; ++j) {
                if constexpr (BF) {
                    const float* rp = Bsf + (size_t)(wn + j * 16 + rl) * 64;
                    float4 f0 = *(const float4*)(rp + ((l0 ^ rl) << 2));
                    float4 f1 = *(const float4*)(rp + (((l0 + 1) ^ rl) << 2));
                    bfr[j] = pack8(f0, f1);
                } else {
                    bfr[j] = *(const s16x8*)(Bs + (wn + j * 16 + rl) * 64 + ko);
                }
            }
#pragma unroll
            for (int i = 0; i < 4; ++i)
#pragma unroll
                for (int j = 0; j < NF; ++j)
                    acc[i][j] = __builtin_amdgcn_mfma_f32_16x16x32_bf16(
                        af[i], bfr[j], acc[i][j], 0, 0, 0);
        }
    }

    // epilogue: D row = (lane>>4)*4 + r, col = lane&15  (verified m89/m91)
    const int cl = lane & 15;
    const int rquad = (lane >> 4) << 2;
#pragma unroll
    for (int tn = 0; tn < NF; ++tn) {
        const int col = n0 + wn + tn * 16 + cl;
        if constexpr (EXP) {
            float csum = 0.f;
#pragma unroll
            for (int tm = 0; tm < 4; ++tm) {
#pragma unroll
                for (int r = 0; r < 4; ++r) {
                    const int row = m0 + wm + tm * 16 + rquad + r;
                    float v = __expf(acc[tm][tn][r] * scale);
                    csum += v;
                    storeC(C + (long long)row * N + col, v);
                }
            }
            csum += __shfl_xor(csum, 16);
            csum += __shfl_xor(csum, 32);
            if ((lane >> 4) == 0)
                atomicAdd(&colsum[(long long)bz * N + col], csum);
        } else {
            float bcol = 0.f;
            if constexpr (BIAS == 1) bcol = bias[(long long)col * bstride];
            float inv = 1.0f;
            if constexpr (CSDIV == 1) inv = 1.0f / colsum[(long long)bz * N + col];
#pragma unroll
            for (int tm = 0; tm < 4; ++tm) {
#pragma unroll
                for (int r = 0; r < 4; ++r) {
                    const int row = m0 + wm + tm * 16 + rquad + r;
                    float v = acc[tm][tn][r] * scale;
                    if constexpr (BIAS == 1) v += bcol;
                    if constexpr (BIAS == 2) v += bias[(long long)row * bstride];
                    if constexpr (CSDIV == 1) v *= inv;
                    if constexpr (CSDIV == 2) v /= colsum[(long long)bz * M + row];
                    storeC(C + (long long)row * N + col, v);
                }
            }
        }
    }
}

// ---------------------------------------------------------------------------
extern "C" void kernel_launch(void* const* d_in, const int* in_sizes, int n_in,
                              void* d_out, int out_size, void* d_ws, size_t ws_size,
                              hipStream_t stream)
{
    constexpr int Bb = 8, NK = 2048, NQ = 2048, D = 256, H = 1024;
    const float scale = 0.03125f;   // 1/sqrt(1024)
    constexpr size_t ES  = (size_t)NK * NQ;       // per-batch scores
    constexpr size_t ET  = (size_t)Bb * NK * D;   // T'/UnT elems (8.39 MB bf16)
    constexpr size_t FIX = 2 * ET * 2             // Tp + UnT
                         + (size_t)512 * 768 * 4  // Cbig
                         + (size_t)512 * 1024 * 2 // Abig (WqT | linb)
                         + (size_t)768 * 1024 * 2 // Bbig (WkT | WvT)
                         + (size_t)8 * NK * 4 + 1024;

    const float* KEY   = (const float*)d_in[0];
    const float* VALUE = (const float*)d_in[1];
    const float* QUERY = (const float*)d_in[2];
    const float* Wk_w  = (const float*)d_in[3];
    const float* Wk_b  = (const float*)d_in[4];
    const float* Wq_w  = (const float*)d_in[5];
    const float* Wq_b  = (const float*)d_in[6];   // cancels in softmax (unused)
    const float* Wv_w  = (const float*)d_in[7];
    const float* Wv_b  = (const float*)d_in[8];
    const float* lin_w = (const float*)d_in[9];
    const float* lin_b = (const float*)d_in[10];
    float* out = (float*)d_out;
    (void)Wq_b; (void)in_sizes; (void)n_in; (void)out_size;

    auto need = [&](int g) -> size_t { return FIX + (size_t)g * ES * 2; };
    const int g = (ws_size >= need(8)) ? 8 : (ws_size >= need(4)) ? 4 : 2;

    char* ws = (char*)d_ws;
    bf16* Sg   = (bf16*)ws;  ws += (size_t)g * ES * 2;     // STexp[k,i] per group
    bf16* Tp   = (bf16*)ws;  ws += ET * 2;                 // T' = KEY@G + vq
    bf16* UnT  = (bf16*)ws;  ws += ET * 2;                 // UnT[d, i] (transposed!)
    float* Cbig= (float*)ws; ws += (size_t)512 * 768 * 4;  // [G|vq ; M2|c2]
    bf16* Abig = (bf16*)ws;  ws += (size_t)512 * 1024 * 2; // [WqT ; linb]
    bf16* Bbig = (bf16*)ws;  ws += (size_t)768 * 1024 * 2; // [WkT ; WvT]
    float* csm = (float*)ws; ws += (size_t)8 * NK * 4;     // column sums
    bf16* WqT  = Abig;
    bf16* linb = Abig + (size_t)256 * 1024;
    bf16* WkT  = Bbig;
    bf16* WvT  = Bbig + (size_t)384 * 1024;
    const float* C1  = Cbig;                               // G^T rows, vq at col 256
    const float* M2  = Cbig + (size_t)256 * 768 + 384;     // M2 rows, c2 at col 640
    const float* vq  = Cbig + 256;
    const float* c2  = Cbig + (size_t)256 * 768 + 640;

    dim3 blk(256);

    // 0: weight transposes + bias/pad rows + lin cvt + zero csm (one launch)
    prep_kernel<<<dim3(256, 5), blk, 0, stream>>>(
        Wk_w, Wk_b, Wq_w, Wv_w, Wv_b, lin_w, WkT, WqT, WvT, linb, csm);

    // 1: Cbig[512,768] = Abig @ Bbig^T (K=1024):
    //    rows 0..255  x cols 0..383   = [G^T | vq]  (WqT . WkT)
    //    rows 256..511 x cols 384..767 = [M2 | c2]  (lin_w . WvT)
    gemm_nt<float, 0, 128><<<dim3(6, 4, 1), blk, 0, stream>>>(
        Abig, Bbig, Cbig, nullptr, 1, nullptr, 512, 768, 1024, 1024, 1024,
        0, 0, 0, 1.0f, 1, 1);

    // 2: T'[i,e] = KEY[i,:] . G^T[e,:] + vq[e]   (A f32, B f32 w/ ldB=768)
    gemm_nt<bf16, 1, 128, 0, 0, 3><<<dim3(2, 128, 1), blk, 0, stream>>>(
        KEY, C1, Tp, vq, 768, nullptr, Bb * NK, D, D, D, 768,
        0, 0, 0, 1.0f, 1, 1);

    // 3..5 per group of g batches
    for (int b0 = 0; b0 < Bb; b0 += g) {
        // 3: STexp[k,i] = exp(scale * QUERY[k,:].T'[i,:]), csm[i] += col sums
        gemm_nt<bf16, 0, 128, 1, 1, 1><<<dim3(g * (NQ / 128) * (NK / 128)), blk, 0, stream>>>(
            QUERY + (size_t)b0 * NQ * D, Tp + (size_t)b0 * NK * D, Sg,
            nullptr, 1, csm + (size_t)b0 * NK,
            NQ, NK, D, D, D,
            (long long)NQ * D, (long long)NK * D, (long long)NQ * NK, scale,
            g, NK / 128);
        // 4: UnT[d,i] = (M2[d,:] . VALUE[i,:] + c2[d]) / csm[i]
        //    (A=M2 f32 ldA=768, B=VALUE f32; row-bias c2 stride 768; col-divide)
        gemm_nt<bf16, 2, 128, 0, 0, 3, 1><<<dim3(g * NK / 128, 2, 1), blk, 0, stream>>>(
            M2, VALUE + (size_t)b0 * NK * D, UnT,
            c2, 768, csm + (size_t)b0 * NK,
            256, g * NK, D, 768, D,
            0, 0, 0, 1.0f, 1, 1);
        // 5: out[k,d] = STexp[k,:] . UnT[d,:]^T + lin_b[d]
        //    (B=UnT ldB=g*NK, per-batch column offset sB=NK; z=bid%g, BN=64)
        gemm_nt<float, 1, 64, 1><<<dim3(g * (NQ / 128) * (D / 64)), blk, 0, stream>>>(
            Sg, UnT, out + (size_t)b0 * NQ * D,
            lin_b, 1, nullptr,
            NQ, D, NK, NK, g * NK,
            (long long)NQ * NK, (long long)NK, (long long)NQ * D, 1.0f,
            g, D / 64);
    }
}

// Round 11
// 221.116 us; speedup vs baseline: 1.7514x; 1.0323x over previous
//
#include <hip/hip_runtime.h>
#include <hip/hip_bf16.h>

using bf16 = __hip_bfloat16;
typedef __attribute__((ext_vector_type(8))) short s16x8;   // 8 bf16 = 4 VGPRs
typedef __attribute__((ext_vector_type(4))) float f32x4;

// ---- async global->LDS 16B copy (wave-uniform LDS base + lane*16) ----
__device__ __forceinline__ void async_cp16(const void* g, void* lds) {
    __builtin_amdgcn_global_load_lds(
        (const __attribute__((address_space(1))) unsigned int*)g,
        (__attribute__((address_space(3))) unsigned int*)lds,
        16, 0, 0);
}

__device__ __forceinline__ void storeC(float* p, float v) { *p = v; }
__device__ __forceinline__ void storeC(bf16* p, float v) { *p = __float2bfloat16(v); }

// pack 8 f32 -> s16x8 bf16 fragment
__device__ __forceinline__ s16x8 pack8(float4 a, float4 b) {
    union { bf16 h[8]; s16x8 v; } o;
    o.h[0] = __float2bfloat16(a.x); o.h[1] = __float2bfloat16(a.y);
    o.h[2] = __float2bfloat16(a.z); o.h[3] = __float2bfloat16(a.w);
    o.h[4] = __float2bfloat16(b.x); o.h[5] = __float2bfloat16(b.y);
    o.h[6] = __float2bfloat16(b.z); o.h[7] = __float2bfloat16(b.w);
    return o.v;
}

// ---------------------------------------------------------------------------
// prep: y=0: WkT[384,1024] = [Wk_w^T ; Wk_b ; 0]
//       y=1: WqT[256,1024] = Wq_w^T
//       y=2: WvT[384,1024] = [Wv_w^T ; Wv_b ; 0]
//       y=3: linb[256,1024] = bf16(lin_w)   y=4: zero csm (16384 f32)
// grid (256, 5) x 256 threads
// ---------------------------------------------------------------------------
__global__ __launch_bounds__(256) void prep_kernel(
    const float* __restrict__ Wk_w, const float* __restrict__ Wk_b,
    const float* __restrict__ Wq_w,
    const float* __restrict__ Wv_w, const float* __restrict__ Wv_b,
    const float* __restrict__ lin_w,
    bf16* __restrict__ WkT, bf16* __restrict__ WqT, bf16* __restrict__ WvT,
    bf16* __restrict__ linb, float* __restrict__ csm)
{
    const int t = threadIdx.x, b = blockIdx.x, y = blockIdx.y;
    if (y <= 2) {
        const float* src = (y == 0) ? Wk_w : (y == 1) ? Wq_w : Wv_w;
        const float* bia = (y == 0) ? Wk_b : Wv_b;
        bf16* dst = (y == 0) ? WkT : (y == 1) ? WqT : WvT;
        if (b < 64) {                       // 64x64 transpose tiles (16 x 4)
            __shared__ float T[64][65];
            const int h0 = (b & 15) * 64, d0 = (b >> 4) * 64;
            const int r = t >> 2, cg = t & 3;
            const float* sp = src + (h0 + r) * 256 + d0 + cg * 16;
#pragma unroll
            for (int c4 = 0; c4 < 4; ++c4) {
                float4 v = *(const float4*)(sp + c4 * 4);
                const int cb = cg * 16 + c4 * 4;
                T[cb + 0][r] = v.x; T[cb + 1][r] = v.y;
                T[cb + 2][r] = v.z; T[cb + 3][r] = v.w;
            }
            __syncthreads();
            union { bf16 h[16]; uint4 u[2]; } o;
#pragma unroll
            for (int j = 0; j < 16; ++j) o.h[j] = __float2bfloat16(T[r][cg * 16 + j]);
            uint4* dp = (uint4*)(dst + (size_t)(d0 + r) * 1024 + h0 + cg * 16);
            dp[0] = o.u[0]; dp[1] = o.u[1];
        } else if (y != 1) {
            if (b < 68) {                   // row 256 = bias
                const int i = (b - 64) * 256 + t;
                dst[256 * 1024 + i] = __float2bfloat16(bia[i]);
            } else if (b < 132) {           // rows 257..383 = 0
                const int i = (b - 68) * 256 + t;
                if (i < 127 * 1024 / 8)
                    ((uint4*)(dst + 257 * 1024))[i] = uint4{0, 0, 0, 0};
            }
        }
    } else if (y == 3) {
        const int i = b * 256 + t;          // 65536 float4 groups
        float4 v = ((const float4*)lin_w)[i];
        union { bf16 h[4]; uint2 u; } o;
        o.h[0] = __float2bfloat16(v.x); o.h[1] = __float2bfloat16(v.y);
        o.h[2] = __float2bfloat16(v.z); o.h[3] = __float2bfloat16(v.w);
        ((uint2*)linb)[i] = o.u;
    } else {
        const int i = b * 256 + t;
        if (i < 4096) ((float4*)csm)[i] = float4{0.f, 0.f, 0.f, 0.f};
    }
}

// ---------------------------------------------------------------------------
// NT GEMM: C[M,N] = scale * (A[M,K] @ B[N,K]^T) + bias
//   Tile 128xBN, BK=64, 256 threads (4 waves), XOR-swizzled LDS (conflict-free)
//   BIAS: 0 none, 1 bias[col*bstride], 2 bias[row*bstride]
//   SWZ: 1 = 1-D grid, z = bid % nz (XCD binding), GROUP_M=4 tile order
//   EXP: 1 = write exp(acc*scale), atomic col sums into colsum[bz*N+col];
//        stores staged through LDS for coalesced 16B writes (needs CVT&1)
//   CVT bit0/bit1: A/B is f32 -> ASYNC-staged f32 LDS tile, converted on read
//   CSDIV: 1 = divide by colsum[bz*N+col], 2 = divide by colsum[bz*M+row]
// ---------------------------------------------------------------------------
template <typename OutT, int BIAS, int BN, int SWZ = 0, int EXP = 0, int CVT = 0,
          int CSDIV = 0>
__global__ __launch_bounds__(256) void gemm_nt(
    const void* __restrict__ Av, const void* __restrict__ Bv,
    OutT* __restrict__ C, const float* __restrict__ bias, int bstride,
    float* __restrict__ colsum,
    int M, int N, int K, int ldA, int ldB,
    long long sA, long long sB, long long sC,
    float scale, int nz, int npn)
{
    constexpr int NF = BN / 32;              // B frags per wave (n-dir)
    constexpr bool AF = (CVT & 1) != 0, BF = (CVT & 2) != 0;
    static_assert(!EXP || (AF && BN == 128), "EXP epilogue reuses 32KB f32 A-LDS");
    __shared__ __align__(16) char AsRaw[AF ? 128 * 64 * 4 : 128 * 64 * 2];
    __shared__ __align__(16) char BsRaw[BF ? BN * 64 * 4 : BN * 64 * 2];
    bf16*  As  = (bf16*)AsRaw;   float* Asf = (float*)AsRaw;
    bf16*  Bs  = (bf16*)BsRaw;   float* Bsf = (float*)BsRaw;

    int bz, m0, n0;
    if constexpr (SWZ) {
        const int bid = blockIdx.x;
        bz = bid % nz;                        // bind batch -> XCD (round-robin)
        const int t0 = bid / nz;
        const int grp = t0 / (4 * npn);       // GROUP_M = 4
        m0 = (grp * 4 + (t0 % 4)) * 128;
        n0 = ((t0 / 4) % npn) * BN;
    } else {
        bz = blockIdx.z;
        m0 = blockIdx.y * 128;
        n0 = blockIdx.x * BN;
    }
    C += sC * bz;

    const bf16*  A16 = nullptr; const float* A32 = nullptr;
    const bf16*  B16 = nullptr; const float* B32 = nullptr;
    if constexpr (AF) A32 = (const float*)Av + sA * bz;
    else              A16 = (const bf16*)Av + sA * bz;
    if constexpr (BF) B32 = (const float*)Bv + sB * bz;
    else              B16 = (const bf16*)Bv + sB * bz;

    const int t = threadIdx.x;
    const int lane = t & 63;
    const int w = t >> 6;                    // wave id 0..3
    const int wm = (w >> 1) * 64;            // wave row offset
    const int wn = (w & 1) * (BN / 2);       // wave col offset

    f32x4 acc[4][NF] = {};

    // bf16 staging: idx = c*256+t -> row = idx>>3, swizzle XOR-(row&7) on 8 chunks
    const int trow = t >> 3;
    const int tcol = (t & 7) ^ (trow & 7);
    // f32 staging: idx = c*256+t -> row = c*16 + (t>>4), swizzle XOR-(t>>4) on 16
    const int t16r = t >> 4;
    const int t16c = (t & 15) ^ t16r;
    char* stA = (char*)AsRaw + (size_t)w * 1024;   // + c*4096 (wave-uniform)
    char* stB = (char*)BsRaw + (size_t)w * 1024;

    for (int k0 = 0; k0 < K; k0 += 64) {
        __syncthreads();   // protect LDS while other waves still compute
        if constexpr (AF) {
            const float* a_src = A32 + (long long)(m0 + t16r) * ldA + k0 + t16c * 4;
#pragma unroll
            for (int c = 0; c < 8; ++c)
                async_cp16(a_src + (long long)(c * 16) * ldA, stA + c * 4096);
        } else {
            const bf16* a_src = A16 + (long long)(m0 + trow) * ldA + k0 + tcol * 8;
#pragma unroll
            for (int c = 0; c < 4; ++c)
                async_cp16(a_src + (long long)(c * 32) * ldA, stA + c * 4096);
        }
        if constexpr (BF) {
            const float* b_src = B32 + (long long)(n0 + t16r) * ldB + k0 + t16c * 4;
#pragma unroll
            for (int c = 0; c < BN / 16; ++c)
                async_cp16(b_src + (long long)(c * 16) * ldB, stB + c * 4096);
        } else {
            const bf16* b_src = B16 + (long long)(n0 + trow) * ldB + k0 + tcol * 8;
#pragma unroll
            for (int c = 0; c < NF; ++c)
                async_cp16(b_src + (long long)(c * 32) * ldB, stB + c * 4096);
        }
        __syncthreads();   // vmcnt drain before s_barrier

        const int rl = lane & 15;
        const int quad = lane >> 4;
        const int sw = rl & 7;
#pragma unroll
        for (int kk = 0; kk < 64; kk += 32) {
            const int c8 = (kk >> 3) + quad;          // bf16 logical chunk (8B)
            const int ko = ((c8 ^ sw) << 3);          // bf16 physical elem offset
            const int l0 = (kk >> 2) + quad * 2;      // f32 logical chunk (16B)
            s16x8 af[4], bfr[NF];
#pragma unroll
            for (int i = 0; i < 4; ++i) {
                if constexpr (AF) {
                    const float* rp = Asf + (size_t)(wm + i * 16 + rl) * 64;
                    float4 f0 = *(const float4*)(rp + ((l0 ^ rl) << 2));
                    float4 f1 = *(const float4*)(rp + (((l0 + 1) ^ rl) << 2));
                    af[i] = pack8(f0, f1);
                } else {
                    af[i] = *(const s16x8*)(As + (wm + i * 16 + rl) * 64 + ko);
                }
            }
#pragma unroll
            for (int j = 0; j < NF; ++j) {
                if constexpr (BF) {
                    const float* rp = Bsf + (size_t)(wn + j * 16 + rl) * 64;
                    float4 f0 = *(const float4*)(rp + ((l0 ^ rl) << 2));
                    float4 f1 = *(const float4*)(rp + (((l0 + 1) ^ rl) << 2));
                    bfr[j] = pack8(f0, f1);
                } else {
                    bfr[j] = *(const s16x8*)(Bs + (wn + j * 16 + rl) * 64 + ko);
                }
            }
#pragma unroll
            for (int i = 0; i < 4; ++i)
#pragma unroll
                for (int j = 0; j < NF; ++j)
                    acc[i][j] = __builtin_amdgcn_mfma_f32_16x16x32_bf16(
                        af[i], bfr[j], acc[i][j], 0, 0, 0);
        }
    }

    // epilogue: D row = (lane>>4)*4 + r, col = lane&15  (verified m89/m91)
    const int cl = lane & 15;
    const int rquad = (lane >> 4) << 2;
    if constexpr (EXP) {
        // pass 1: exp in place + column sums + atomics (layout unchanged)
#pragma unroll
        for (int tn = 0; tn < NF; ++tn) {
            const int col = n0 + wn + tn * 16 + cl;
            float csum = 0.f;
#pragma unroll
            for (int tm = 0; tm < 4; ++tm) {
#pragma unroll
                for (int r = 0; r < 4; ++r) {
                    float v = __expf(acc[tm][tn][r] * scale);
                    acc[tm][tn][r] = v;
                    csum += v;
                }
            }
            csum += __shfl_xor(csum, 16);
            csum += __shfl_xor(csum, 32);
            if ((lane >> 4) == 0)
                atomicAdd(&colsum[(long long)bz * N + col], csum);
        }
        // pass 2: staged coalesced stores via f32 A-LDS (32KB >= 32*132*4)
        float* Ls = (float*)AsRaw;
        const int srow = t >> 3;             // 0..31
        const int scol = (t & 7) * 16;       // 0..112
        const int grb = m0 + ((srow & 16) ? 64 : 0) + (srow & 15);
#pragma unroll
        for (int tm = 0; tm < 4; ++tm) {
            __syncthreads();                 // LDS free / prev pass read done
#pragma unroll
            for (int tn = 0; tn < NF; ++tn)
#pragma unroll
                for (int r = 0; r < 4; ++r)
                    Ls[((w >> 1) * 16 + rquad + r) * 132 + wn + tn * 16 + cl] =
                        acc[tm][tn][r];
            __syncthreads();
            float4 f0 = *(const float4*)&Ls[srow * 132 + scol];
            float4 f1 = *(const float4*)&Ls[srow * 132 + scol + 4];
            float4 f2 = *(const float4*)&Ls[srow * 132 + scol + 8];
            float4 f3 = *(const float4*)&Ls[srow * 132 + scol + 12];
            union { s16x8 v; uint4 u; } p0, p1;
            p0.v = pack8(f0, f1);  p1.v = pack8(f2, f3);
            uint4* dst = (uint4*)((bf16*)C + (long long)(grb + tm * 16) * N + n0 + scol);
            dst[0] = p0.u;
            dst[1] = p1.u;
        }
    } else {
#pragma unroll
        for (int tn = 0; tn < NF; ++tn) {
            const int col = n0 + wn + tn * 16 + cl;
            float bcol = 0.f;
            if constexpr (BIAS == 1) bcol = bias[(long long)col * bstride];
            float inv = 1.0f;
            if constexpr (CSDIV == 1) inv = 1.0f / colsum[(long long)bz * N + col];
#pragma unroll
            for (int tm = 0; tm < 4; ++tm) {
#pragma unroll
                for (int r = 0; r < 4; ++r) {
                    const int row = m0 + wm + tm * 16 + rquad + r;
                    float v = acc[tm][tn][r] * scale;
                    if constexpr (BIAS == 1) v += bcol;
                    if constexpr (BIAS == 2) v += bias[(long long)row * bstride];
                    if constexpr (CSDIV == 1) v *= inv;
                    if constexpr (CSDIV == 2) v /= colsum[(long long)bz * M + row];
                    storeC(C + (long long)row * N + col, v);
                }
            }
        }
    }
}

// ---------------------------------------------------------------------------
extern "C" void kernel_launch(void* const* d_in, const int* in_sizes, int n_in,
                              void* d_out, int out_size, void* d_ws, size_t ws_size,
                              hipStream_t stream)
{
    constexpr int Bb = 8, NK = 2048, NQ = 2048, D = 256, H = 1024;
    const float scale = 0.03125f;   // 1/sqrt(1024)
    constexpr size_t ES  = (size_t)NK * NQ;       // per-batch scores
    constexpr size_t ET  = (size_t)Bb * NK * D;   // T'/UnT elems (8.39 MB bf16)
    constexpr size_t FIX = 2 * ET * 2             // Tp + UnT
                         + (size_t)512 * 768 * 4  // Cbig
                         + (size_t)512 * 1024 * 2 // Abig (WqT | linb)
                         + (size_t)768 * 1024 * 2 // Bbig (WkT | WvT)
                         + (size_t)8 * NK * 4 + 1024;

    const float* KEY   = (const float*)d_in[0];
    const float* VALUE = (const float*)d_in[1];
    const float* QUERY = (const float*)d_in[2];
    const float* Wk_w  = (const float*)d_in[3];
    const float* Wk_b  = (const float*)d_in[4];
    const float* Wq_w  = (const float*)d_in[5];
    const float* Wq_b  = (const float*)d_in[6];   // cancels in softmax (unused)
    const float* Wv_w  = (const float*)d_in[7];
    const float* Wv_b  = (const float*)d_in[8];
    const float* lin_w = (const float*)d_in[9];
    const float* lin_b = (const float*)d_in[10];
    float* out = (float*)d_out;
    (void)Wq_b; (void)in_sizes; (void)n_in; (void)out_size;

    auto need = [&](int g) -> size_t { return FIX + (size_t)g * ES * 2; };
    const int g = (ws_size >= need(8)) ? 8 : (ws_size >= need(4)) ? 4 : 2;

    char* ws = (char*)d_ws;
    bf16* Sg   = (bf16*)ws;  ws += (size_t)g * ES * 2;     // STexp[k,i] per group
    bf16* Tp   = (bf16*)ws;  ws += ET * 2;                 // T' = KEY@G + vq
    bf16* UnT  = (bf16*)ws;  ws += ET * 2;                 // UnT[d, i] (transposed)
    float* Cbig= (float*)ws; ws += (size_t)512 * 768 * 4;  // [G|vq ; M2|c2]
    bf16* Abig = (bf16*)ws;  ws += (size_t)512 * 1024 * 2; // [WqT ; linb]
    bf16* Bbig = (bf16*)ws;  ws += (size_t)768 * 1024 * 2; // [WkT ; WvT]
    float* csm = (float*)ws; ws += (size_t)8 * NK * 4;     // column sums
    bf16* WqT  = Abig;
    bf16* linb = Abig + (size_t)256 * 1024;
    bf16* WkT  = Bbig;
    bf16* WvT  = Bbig + (size_t)384 * 1024;
    const float* C1  = Cbig;                               // G^T rows, vq at col 256
    const float* M2  = Cbig + (size_t)256 * 768 + 384;     // M2 rows, c2 at col 640
    const float* vq  = Cbig + 256;
    const float* c2  = Cbig + (size_t)256 * 768 + 640;

    dim3 blk(256);

    // 0: weight transposes + bias/pad rows + lin cvt + zero csm (one launch)
    prep_kernel<<<dim3(256, 5), blk, 0, stream>>>(
        Wk_w, Wk_b, Wq_w, Wv_w, Wv_b, lin_w, WkT, WqT, WvT, linb, csm);

    // 1: Cbig[512,768] = Abig @ Bbig^T (K=1024):
    //    rows 0..255  x cols 0..383   = [G^T | vq]  (WqT . WkT)
    //    rows 256..511 x cols 384..767 = [M2 | c2]  (lin_w . WvT)
    gemm_nt<float, 0, 128><<<dim3(6, 4, 1), blk, 0, stream>>>(
        Abig, Bbig, Cbig, nullptr, 1, nullptr, 512, 768, 1024, 1024, 1024,
        0, 0, 0, 1.0f, 1, 1);

    // 2: T'[i,e] = KEY[i,:] . G^T[e,:] + vq[e]   (A f32, B f32 w/ ldB=768; BN=64)
    gemm_nt<bf16, 1, 64, 0, 0, 3><<<dim3(4, 128, 1), blk, 0, stream>>>(
        KEY, C1, Tp, vq, 768, nullptr, Bb * NK, D, D, D, 768,
        0, 0, 0, 1.0f, 1, 1);

    // 3..5 per group of g batches
    for (int b0 = 0; b0 < Bb; b0 += g) {
        // 3: STexp[k,i] = exp(scale * QUERY[k,:].T'[i,:]), csm[i] += col sums
        //    (coalesced LDS-staged stores)
        gemm_nt<bf16, 0, 128, 1, 1, 1><<<dim3(g * (NQ / 128) * (NK / 128)), blk, 0, stream>>>(
            QUERY + (size_t)b0 * NQ * D, Tp + (size_t)b0 * NK * D, Sg,
            nullptr, 1, csm + (size_t)b0 * NK,
            NQ, NK, D, D, D,
            (long long)NQ * D, (long long)NK * D, (long long)NQ * NK, scale,
            g, NK / 128);
        // 4: UnT[d,i] = (M2[d,:] . VALUE[i,:] + c2[d]) / csm[i]   (BN=64)
        gemm_nt<bf16, 2, 64, 0, 0, 3, 1><<<dim3(g * NK / 64, 2, 1), blk, 0, stream>>>(
            M2, VALUE + (size_t)b0 * NK * D, UnT,
            c2, 768, csm + (size_t)b0 * NK,
            256, g * NK, D, 768, D,
            0, 0, 0, 1.0f, 1, 1);
        // 5: out[k,d] = STexp[k,:] . UnT[d,:]^T + lin_b[d]
        //    (B=UnT ldB=g*NK, per-batch column offset sB=NK; z=bid%g, BN=64)
        gemm_nt<float, 1, 64, 1><<<dim3(g * (NQ / 128) * (D / 64)), blk, 0, stream>>>(
            Sg, UnT, out + (size_t)b0 * NQ * D,
            lin_b, 1, nullptr,
            NQ, D, NK, NK, g * NK,
            (long long)NQ * NK, (long long)NK, (long long)NQ * D, 1.0f,
            g, D / 64);
    }
}